// Round 13
// baseline (101.744 us; speedup 1.0000x reference)
//
#include <hip/hip_runtime.h>

// B=256, F=32, N=16, D=512
//   sims[b,f,c,n] = relu(face[b,f]·ner[c,n])      (8192 x 4096 NT GEMM, K=512)
//   S_all[b,f]    = sum_{c,n} masked(sims)        (masked: ==1.0 -> 0)
//   pos[b,f]      = sum_n sims[b,f,b,n]           (unmasked diagonal)
//   diag_m[b,f]   = sum_n masked(sims[b,f,b,n])
//   loss = sum(relu((S_all-diag_m)/255 - pos + 0.2) * face_mask) / 256
//
// Round 13: A-DIRECT-TO-REGISTERS hybrid. B keeps r2's proven LDS path
// (8 KB/tile dbuf, 0-conflict swizzle, 2 gload_lds/wave/tile, barriers pin
// the schedule); A-fragments load straight global->VGPR with a 2-K-tile
// register prefetch (3 rotating named sets, full unroll, static indexing).
// Halves LDS writes + ds_read count vs r2; LDS 16 KB -> 3 blocks/CU;
// counted vmcnt(4) per iter (A(t+2) stays in flight). Diag fused (r6-
// verified); merged cvt; r2 math end-to-end (absmax 0.0 expected).

#define DIM_D 512
#define M_TOT 8192
#define N_TOT 4096

typedef __attribute__((ext_vector_type(8))) short short8v;
typedef __attribute__((ext_vector_type(4))) float f32x4;

__device__ __forceinline__ unsigned short f2bf(float f) {
  unsigned int u = __builtin_bit_cast(unsigned int, f);
  u += 0x7fffu + ((u >> 16) & 1u);
  return (unsigned short)(u >> 16);
}

// ---------------------------------------------------------------------------
// Merged cvt: face+ner fp32 -> bf16, plus face_mask (fp32 row-sum != 0).
// ---------------------------------------------------------------------------
__global__ __launch_bounds__(256) void cvt_all(
    const float* __restrict__ face, const float* __restrict__ ner,
    unsigned short* __restrict__ face_bf, unsigned short* __restrict__ ner_bf,
    float* __restrict__ mask) {
  const int gw = blockIdx.x * 4 + (threadIdx.x >> 6);
  const int lane = threadIdx.x & 63;
  const bool isFace = gw < M_TOT;
  const int row = isFace ? gw : gw - M_TOT;
  const float* src = (isFace ? face : ner) + (size_t)row * DIM_D;
  unsigned short* dst = (isFace ? face_bf : ner_bf) + (size_t)row * DIM_D;

  const float4 f0 = ((const float4*)src)[lane * 2];
  const float4 f1 = ((const float4*)src)[lane * 2 + 1];
  short8v o;
  o[0] = (short)f2bf(f0.x); o[1] = (short)f2bf(f0.y);
  o[2] = (short)f2bf(f0.z); o[3] = (short)f2bf(f0.w);
  o[4] = (short)f2bf(f1.x); o[5] = (short)f2bf(f1.y);
  o[6] = (short)f2bf(f1.z); o[7] = (short)f2bf(f1.w);
  *(short8v*)(dst + lane * 8) = o;

  if (isFace) {
    float fs = f0.x + f0.y + f0.z + f0.w + f1.x + f1.y + f1.z + f1.w;
#pragma unroll
    for (int off = 1; off < 64; off <<= 1) fs += __shfl_xor(fs, off);
    if (lane == 0) mask[row] = (fs != 0.0f) ? 1.0f : 0.0f;
  }
}

// ---------------------------------------------------------------------------
// Hybrid GEMM: 128x128 tile, BK=32, 4 waves (2x2), wave-tile 64x64.
// B LDS (16 KB): buffer p (p = t&1) at p*4096 shorts; 128 rows x 4 slots x 8;
// slot s of row r holds k-slot s ^ ((r>>1)&3)  [r2-measured 0 conflicts].
// A: per-lane direct global loads, frag row = m0+wr*64+mi*16+(lane&15),
// k-offset = t*32 + (lane>>4)*8 (16B) -- 16 rows x 64B pattern, L2-served.
// ---------------------------------------------------------------------------
#define MFMA(A_, B_, C_) __builtin_amdgcn_mfma_f32_16x16x32_bf16(A_, B_, C_, 0, 0, 0)

#define GLDS(SRC, DSTOFF)                                                     \
  __builtin_amdgcn_global_load_lds(                                           \
      (const __attribute__((address_space(1))) void*)(SRC),                   \
      (__attribute__((address_space(3))) void*)(Blds + (DSTOFF)), 16, 0, 0)

__global__ __launch_bounds__(256, 2) void grl_hybrid(
    const unsigned short* __restrict__ A, const unsigned short* __restrict__ Bn,
    float* __restrict__ S_all, float* __restrict__ pos,
    float* __restrict__ diagm) {
  __shared__ __align__(16) unsigned short Blds[2 * 4096];  // 16 KB

  const int tid = threadIdx.x;
  const int lane = tid & 63;
  const int wid = tid >> 6;
  const int wr = wid >> 1;   // 0..1 (M)
  const int wc = wid & 1;    // 0..1 (N)
  const int bx = blockIdx.x;
  const int by = blockIdx.y;
  const int m0 = bx * 128;
  const int n0 = by * 128;

  // ---- B stager (r2-proven): 2 gload_lds per wave per K-tile ------------
  // instr i covers rows [wid*32+i*16, +16): row = wid*32+i*16+(lane>>2),
  // slot = lane&3, source k-slot g = (lane&3) ^ ((row>>1)&3)
  const int g = (lane & 3) ^ ((lane >> 3) & 3);
  const int r0 = wid * 32 + (lane >> 2);
  const unsigned short* gB0 = Bn + (size_t)(n0 + r0) * DIM_D + g * 8;
  const unsigned short* gB1 = gB0 + (size_t)16 * DIM_D;

#define STAGE_B(T)                                             \
  do {                                                         \
    const int p_ = ((T)&1) * 4096;                             \
    GLDS(gB0 + (T) * 32, p_ + (wid * 2 + 0) * 512);            \
    GLDS(gB1 + (T) * 32, p_ + (wid * 2 + 1) * 512);            \
  } while (0)

  // ---- B reader (r2-proven swizzle) -------------------------------------
  const int boff = (lane & 15) * 32 + (((lane >> 4) ^ ((lane >> 1) & 3)) * 8);
  short8v b0, b1, b2, b3;

#define LOADB(T)                                                          \
  do {                                                                    \
    const unsigned short* Bb_ = Blds + ((T)&1) * 4096 + (wc * 64) * 32 + boff; \
    b0 = *(const short8v*)(Bb_);                                          \
    b1 = *(const short8v*)(Bb_ + 512);                                    \
    b2 = *(const short8v*)(Bb_ + 1024);                                   \
    b3 = *(const short8v*)(Bb_ + 1536);                                   \
  } while (0)

  // ---- A direct loads ---------------------------------------------------
  const unsigned short* pA =
      A + (size_t)(m0 + wr * 64 + (lane & 15)) * DIM_D + (lane >> 4) * 8;

#define LOADA(SET, T)                                                     \
  do {                                                                    \
    SET##0 = *(const short8v*)(pA + 0 * (16 * DIM_D) + (T) * 32);         \
    SET##1 = *(const short8v*)(pA + 1 * (16 * DIM_D) + (T) * 32);         \
    SET##2 = *(const short8v*)(pA + 2 * (16 * DIM_D) + (T) * 32);         \
    SET##3 = *(const short8v*)(pA + 3 * (16 * DIM_D) + (T) * 32);         \
  } while (0)

  f32x4 acc[4][4];
#pragma unroll
  for (int i = 0; i < 4; ++i)
#pragma unroll
    for (int j = 0; j < 4; ++j) acc[i][j] = (f32x4){0.f, 0.f, 0.f, 0.f};

  short8v aP0, aP1, aP2, aP3, aQ0, aQ1, aQ2, aQ3, aR0, aR1, aR2, aR3;

#define MFMA16(SET)                                  \
  acc[0][0] = MFMA(SET##0, b0, acc[0][0]);           \
  acc[0][1] = MFMA(SET##0, b1, acc[0][1]);           \
  acc[0][2] = MFMA(SET##0, b2, acc[0][2]);           \
  acc[0][3] = MFMA(SET##0, b3, acc[0][3]);           \
  acc[1][0] = MFMA(SET##1, b0, acc[1][0]);           \
  acc[1][1] = MFMA(SET##1, b1, acc[1][1]);           \
  acc[1][2] = MFMA(SET##1, b2, acc[1][2]);           \
  acc[1][3] = MFMA(SET##1, b3, acc[1][3]);           \
  acc[2][0] = MFMA(SET##2, b0, acc[2][0]);           \
  acc[2][1] = MFMA(SET##2, b1, acc[2][1]);           \
  acc[2][2] = MFMA(SET##2, b2, acc[2][2]);           \
  acc[2][3] = MFMA(SET##2, b3, acc[2][3]);           \
  acc[3][0] = MFMA(SET##3, b0, acc[3][0]);           \
  acc[3][1] = MFMA(SET##3, b1, acc[3][1]);           \
  acc[3][2] = MFMA(SET##3, b2, acc[3][2]);           \
  acc[3][3] = MFMA(SET##3, b3, acc[3][3]);

// Main iteration: read B(t) frags; stage B(t+1); prefetch A(t+2); 16 MFMA
// on A(t) (loaded 2 iters ago); counted vmcnt so only A(t+2) stays in
// flight across the barrier (B(t+1) must have landed).
#define ITER(T, CUR, NXT, KEEP)                                           \
  do {                                                                    \
    LOADB(T);                                                             \
    if ((T) + 1 < 16) STAGE_B((T) + 1);                                   \
    if ((T) + 2 < 16) LOADA(NXT, (T) + 2);                                \
    MFMA16(CUR);                                                          \
    asm volatile("s_waitcnt vmcnt(" KEEP ")" ::: "memory");               \
    __builtin_amdgcn_s_barrier();                                         \
  } while (0)

  // ---- prologue: A(0),A(1) to regs; B(0) staged; drain once -------------
  LOADA(aP, 0);
  LOADA(aQ, 1);
  STAGE_B(0);
  asm volatile("s_waitcnt vmcnt(0)" ::: "memory");
  __builtin_amdgcn_s_barrier();

  // ---- 16 K-tiles, A sets rotate P->Q->R with period 3 ------------------
  ITER(0, aP, aR, "4");
  ITER(1, aQ, aP, "4");
  ITER(2, aR, aQ, "4");
  ITER(3, aP, aR, "4");
  ITER(4, aQ, aP, "4");
  ITER(5, aR, aQ, "4");
  ITER(6, aP, aR, "4");
  ITER(7, aQ, aP, "4");
  ITER(8, aR, aQ, "4");
  ITER(9, aP, aR, "4");
  ITER(10, aQ, aP, "4");
  ITER(11, aR, aQ, "4");
  ITER(12, aP, aR, "4");
  ITER(13, aQ, aP, "4");
  ITER(14, aR, aQ, "0");  // stages B(15), no A load -> drain to 0
  // t=15: last tile, no staging, no trailing barrier
  LOADB(15);
  MFMA16(aP);

  // ---- fused relu + (==1 -> 0) + per-thread row sums --------------------
  // C/D layout: col = lane&15 (n), row(frag) = (lane>>4)*4 + reg
  float rs[4][4];
#pragma unroll
  for (int mi = 0; mi < 4; ++mi)
#pragma unroll
    for (int r = 0; r < 4; ++r) rs[mi][r] = 0.0f;
#pragma unroll
  for (int mi = 0; mi < 4; ++mi)
#pragma unroll
    for (int ni = 0; ni < 4; ++ni)
#pragma unroll
      for (int r = 0; r < 4; ++r) {
        float v = acc[mi][ni][r];
        v = v > 0.0f ? v : 0.0f;
        v = (v == 1.0f) ? 0.0f : v;
        rs[mi][r] += v;
      }
#pragma unroll
  for (int mi = 0; mi < 4; ++mi)
#pragma unroll
    for (int r = 0; r < 4; ++r) {
      float s = rs[mi][r];
      s += __shfl_xor(s, 1);
      s += __shfl_xor(s, 2);
      s += __shfl_xor(s, 4);
      s += __shfl_xor(s, 8);
      if ((lane & 15) == 0)
        atomicAdd(&S_all[m0 + wr * 64 + mi * 16 + (lane >> 4) * 4 + r], s);
    }

  // ---- fused diagonal (blocks with by == bx>>1 only; r6-verified) -------
  if (by == (bx >> 1)) {
#pragma unroll
    for (int mi = 0; mi < 4; ++mi) {
      const int R0 = m0 + wr * 64 + mi * 16;  // rows R0..R0+15 share b_
      const int tc = ((R0 >> 5) << 4) - n0;   // in [0,128)
      if ((tc >> 6) == wc) {
        const int dn = (tc >> 4) & 3;
#pragma unroll
        for (int ni = 0; ni < 4; ++ni)
          if (ni == dn) {
#pragma unroll
            for (int r = 0; r < 4; ++r) {
              float v = acc[mi][ni][r];
              v = v > 0.0f ? v : 0.0f;
              float vm = (v == 1.0f) ? 0.0f : v;
              float ps = v, ds = vm;
              ps += __shfl_xor(ps, 1); ds += __shfl_xor(ds, 1);
              ps += __shfl_xor(ps, 2); ds += __shfl_xor(ds, 2);
              ps += __shfl_xor(ps, 4); ds += __shfl_xor(ds, 4);
              ps += __shfl_xor(ps, 8); ds += __shfl_xor(ds, 8);
              if ((lane & 15) == 0) {
                const int R = R0 + (lane >> 4) * 4 + r;
                pos[R] = ps;
                diagm[R] = ds;
              }
            }
          }
      }
    }
  }
}

// ---------------------------------------------------------------------------
// Finalize: rank + global sum. Single block, 1024 threads.
// ---------------------------------------------------------------------------
__global__ __launch_bounds__(1024) void grl_final(
    const float* __restrict__ S_all, const float* __restrict__ diagm,
    const float* __restrict__ pos, const float* __restrict__ mask,
    float* __restrict__ out) {
  __shared__ float red[16];
  const int lane = threadIdx.x & 63;
  const int wv = threadIdx.x >> 6;
  float s = 0.0f;
  for (int r = threadIdx.x; r < M_TOT; r += 1024) {
    const float neg = (S_all[r] - diagm[r]) / 255.0f;  // 255 + 1e-8 == 255.0f
    float rank = neg - pos[r] + 0.2f;
    rank = rank > 0.0f ? rank : 0.0f;
    s += rank * mask[r];
  }
#pragma unroll
  for (int off = 1; off < 64; off <<= 1) s += __shfl_xor(s, off);
  if (lane == 0) red[wv] = s;
  __syncthreads();
  if (threadIdx.x == 0) {
    float t = 0.0f;
#pragma unroll
    for (int i = 0; i < 16; ++i) t += red[i];
    out[0] = t / 256.0f;  // BETA * sum / B
  }
}

// ---------------------------------------------------------------------------
extern "C" void kernel_launch(void* const* d_in, const int* in_sizes, int n_in,
                              void* d_out, int out_size, void* d_ws, size_t ws_size,
                              hipStream_t stream) {
  const float* face = (const float*)d_in[0];
  const float* ner = (const float*)d_in[1];

  unsigned short* face_bf = (unsigned short*)d_ws;
  unsigned short* ner_bf = face_bf + (size_t)M_TOT * DIM_D;
  float* S_all = (float*)(ner_bf + (size_t)N_TOT * DIM_D);
  float* diagm = S_all + M_TOT;
  float* pos = diagm + M_TOT;
  float* mask = pos + M_TOT;

  hipMemsetAsync(S_all, 0, M_TOT * sizeof(float), stream);
  cvt_all<<<(M_TOT + N_TOT) / 4, 256, 0, stream>>>(face, ner, face_bf, ner_bf,
                                                   mask);
  grl_hybrid<<<dim3(M_TOT / 128, N_TOT / 128), 256, 0, stream>>>(
      face_bf, ner_bf, S_all, pos, diagm);
  grl_final<<<1, 1024, 0, stream>>>(S_all, diagm, pos, mask, (float*)d_out);
}

// Round 14
// 86.808 us; speedup vs baseline: 1.1721x; 1.1721x over previous
//
#include <hip/hip_runtime.h>

// B=256, F=32, N=16, D=512
//   sims[b,f,c,n] = relu(face[b,f]·ner[c,n])      (8192 x 4096 NT GEMM, K=512)
//   S_all[b,f]    = sum_{c,n} masked(sims)        (masked: ==1.0 -> 0)
//   pos[b,f]      = sum_n sims[b,f,b,n]           (unmasked diagonal)
//   diag_m[b,f]   = sum_n masked(sims[b,f,b,n])
//   loss = sum(relu((S_all-diag_m)/255 - pos + 0.2) * face_mask) / 256
//
// Round 14: SINGLE-WAVE workgroups -- zero barriers, zero inter-wave hazards.
// Each 64-thread block owns a 64x64 tile; 16 KB wave-private LDS double
// buffer; per K-tile: {stage t+1 (8 gload_lds) -> counted vmcnt(8) ->
// 8 ds_read_b128 + 16 MFMA}. WAR safety is same-wave program order.
// ~10 independent waves/CU overlap each other's stalls (TLP, not barriers).
// r2-proven swizzle + fragment maps + epilogue; diag fused; memset folded
// into cvt.

#define DIM_D 512
#define M_TOT 8192
#define N_TOT 4096

typedef __attribute__((ext_vector_type(8))) short short8v;
typedef __attribute__((ext_vector_type(4))) float f32x4;

__device__ __forceinline__ unsigned short f2bf(float f) {
  unsigned int u = __builtin_bit_cast(unsigned int, f);
  u += 0x7fffu + ((u >> 16) & 1u);
  return (unsigned short)(u >> 16);
}

// ---------------------------------------------------------------------------
// Merged cvt: face+ner fp32 -> bf16, face_mask, and S_all zeroing (replaces
// the separate memset dispatch; stream-ordered before the GEMM).
// ---------------------------------------------------------------------------
__global__ __launch_bounds__(256) void cvt_all(
    const float* __restrict__ face, const float* __restrict__ ner,
    unsigned short* __restrict__ face_bf, unsigned short* __restrict__ ner_bf,
    float* __restrict__ mask, float* __restrict__ S_all) {
  if (blockIdx.x < 8) {  // 8 blocks x 1024 floats = 8192 = S_all
    const int i = blockIdx.x * 1024 + threadIdx.x * 4;
    *(float4*)(S_all + i) = (float4){0.f, 0.f, 0.f, 0.f};
  }
  const int gw = blockIdx.x * 4 + (threadIdx.x >> 6);
  const int lane = threadIdx.x & 63;
  const bool isFace = gw < M_TOT;
  const int row = isFace ? gw : gw - M_TOT;
  const float* src = (isFace ? face : ner) + (size_t)row * DIM_D;
  unsigned short* dst = (isFace ? face_bf : ner_bf) + (size_t)row * DIM_D;

  const float4 f0 = ((const float4*)src)[lane * 2];
  const float4 f1 = ((const float4*)src)[lane * 2 + 1];
  short8v o;
  o[0] = (short)f2bf(f0.x); o[1] = (short)f2bf(f0.y);
  o[2] = (short)f2bf(f0.z); o[3] = (short)f2bf(f0.w);
  o[4] = (short)f2bf(f1.x); o[5] = (short)f2bf(f1.y);
  o[6] = (short)f2bf(f1.z); o[7] = (short)f2bf(f1.w);
  *(short8v*)(dst + lane * 8) = o;

  if (isFace) {
    float fs = f0.x + f0.y + f0.z + f0.w + f1.x + f1.y + f1.z + f1.w;
#pragma unroll
    for (int off = 1; off < 64; off <<= 1) fs += __shfl_xor(fs, off);
    if (lane == 0) mask[row] = (fs != 0.0f) ? 1.0f : 0.0f;
  }
}

// ---------------------------------------------------------------------------
// Single-wave GEMM: 64x64 tile, BK=32, 16 K-tiles.
// LDS buffer p (p = t&1) at p*4096 shorts: A rows [0,2048), B [2048,4096);
// row r at r*32 shorts, 4 slots of 8 bf16; slot s of row r holds global
// k-slot s ^ ((r>>1)&3)  [r2-measured 0 conflicts]. Pre-swizzled source,
// linear LDS dst (rule #21).
// ---------------------------------------------------------------------------
#define MFMA(A_, B_, C_) __builtin_amdgcn_mfma_f32_16x16x32_bf16(A_, B_, C_, 0, 0, 0)

#define GLDS(SRC, DSTOFF)                                                     \
  __builtin_amdgcn_global_load_lds(                                           \
      (const __attribute__((address_space(1))) void*)(SRC),                   \
      (__attribute__((address_space(3))) void*)(lds + (DSTOFF)), 16, 0, 0)

__global__ __launch_bounds__(64) void grl_wave(
    const unsigned short* __restrict__ A, const unsigned short* __restrict__ Bn,
    float* __restrict__ S_all, float* __restrict__ pos,
    float* __restrict__ diagm) {
  __shared__ __align__(16) unsigned short lds[2 * 4096];  // 16 KB

  const int lane = threadIdx.x;
  const int m0 = blockIdx.x * 64;   // M tile (128 of them)
  const int n0 = blockIdx.y * 64;   // N tile (64 of them)

  // ---- stager: 4 instrs per matrix per K-tile; instr i covers 16 rows ---
  // lane -> row = i*16 + (lane>>2), slot = lane&3;
  // source k-slot g = (lane&3) ^ ((row>>1)&3) = (lane&3) ^ ((lane>>3)&3)
  const int g = (lane & 3) ^ ((lane >> 3) & 3);
  const int srow = lane >> 2;  // 0..15
  const unsigned short* gA = A + (size_t)(m0 + srow) * DIM_D + g * 8;
  const unsigned short* gB = Bn + (size_t)(n0 + srow) * DIM_D + g * 8;

#define STAGE(T)                                                         \
  do {                                                                   \
    const int p_ = ((T)&1) * 4096;                                       \
    _Pragma("unroll") for (int i_ = 0; i_ < 4; ++i_) {                   \
      GLDS(gA + (T) * 32 + (size_t)i_ * 16 * DIM_D, p_ + i_ * 512);      \
      GLDS(gB + (T) * 32 + (size_t)i_ * 16 * DIM_D, p_ + 2048 + i_ * 512); \
    }                                                                    \
  } while (0)

  // ---- reader: frag row = mi*16 + (lane&15); k-slot = lane>>4, swizzled -
  const int fo = (lane & 15) * 32 + (((lane >> 4) ^ ((lane >> 1) & 3)) * 8);

  f32x4 acc[4][4];
#pragma unroll
  for (int i = 0; i < 4; ++i)
#pragma unroll
    for (int j = 0; j < 4; ++j) acc[i][j] = (f32x4){0.f, 0.f, 0.f, 0.f};

// One K-tile: 8 ds_read_b128 + 16 MFMA; compiler inserts lgkmcnt.
#define KITER(T, KEEP)                                                   \
  do {                                                                   \
    if ((T) < 15) STAGE((T) + 1);                                        \
    asm volatile("s_waitcnt vmcnt(" KEEP ")" ::: "memory");              \
    const unsigned short* Lb = lds + ((T)&1) * 4096;                     \
    short8v a0 = *(const short8v*)(Lb + 0 * 512 + fo);                   \
    short8v a1 = *(const short8v*)(Lb + 1 * 512 + fo);                   \
    short8v a2 = *(const short8v*)(Lb + 2 * 512 + fo);                   \
    short8v a3 = *(const short8v*)(Lb + 3 * 512 + fo);                   \
    short8v b0 = *(const short8v*)(Lb + 2048 + 0 * 512 + fo);            \
    short8v b1 = *(const short8v*)(Lb + 2048 + 1 * 512 + fo);            \
    short8v b2 = *(const short8v*)(Lb + 2048 + 2 * 512 + fo);            \
    short8v b3 = *(const short8v*)(Lb + 2048 + 3 * 512 + fo);            \
    acc[0][0] = MFMA(a0, b0, acc[0][0]);                                 \
    acc[0][1] = MFMA(a0, b1, acc[0][1]);                                 \
    acc[0][2] = MFMA(a0, b2, acc[0][2]);                                 \
    acc[0][3] = MFMA(a0, b3, acc[0][3]);                                 \
    acc[1][0] = MFMA(a1, b0, acc[1][0]);                                 \
    acc[1][1] = MFMA(a1, b1, acc[1][1]);                                 \
    acc[1][2] = MFMA(a1, b2, acc[1][2]);                                 \
    acc[1][3] = MFMA(a1, b3, acc[1][3]);                                 \
    acc[2][0] = MFMA(a2, b0, acc[2][0]);                                 \
    acc[2][1] = MFMA(a2, b1, acc[2][1]);                                 \
    acc[2][2] = MFMA(a2, b2, acc[2][2]);                                 \
    acc[2][3] = MFMA(a2, b3, acc[2][3]);                                 \
    acc[3][0] = MFMA(a3, b0, acc[3][0]);                                 \
    acc[3][1] = MFMA(a3, b1, acc[3][1]);                                 \
    acc[3][2] = MFMA(a3, b2, acc[3][2]);                                 \
    acc[3][3] = MFMA(a3, b3, acc[3][3]);                                 \
  } while (0)

  STAGE(0);
  KITER(0, "8");   KITER(1, "8");   KITER(2, "8");   KITER(3, "8");
  KITER(4, "8");   KITER(5, "8");   KITER(6, "8");   KITER(7, "8");
  KITER(8, "8");   KITER(9, "8");   KITER(10, "8");  KITER(11, "8");
  KITER(12, "8");  KITER(13, "8");  KITER(14, "8");  KITER(15, "0");

  // ---- fused relu + (==1 -> 0) + per-thread row sums --------------------
  // C/D layout: col = lane&15 (n), row(frag) = (lane>>4)*4 + reg
  float rs[4][4];
#pragma unroll
  for (int mi = 0; mi < 4; ++mi)
#pragma unroll
    for (int r = 0; r < 4; ++r) rs[mi][r] = 0.0f;
#pragma unroll
  for (int mi = 0; mi < 4; ++mi)
#pragma unroll
    for (int ni = 0; ni < 4; ++ni)
#pragma unroll
      for (int r = 0; r < 4; ++r) {
        float v = acc[mi][ni][r];
        v = v > 0.0f ? v : 0.0f;
        v = (v == 1.0f) ? 0.0f : v;
        rs[mi][r] += v;
      }
#pragma unroll
  for (int mi = 0; mi < 4; ++mi)
#pragma unroll
    for (int r = 0; r < 4; ++r) {
      float s = rs[mi][r];
      s += __shfl_xor(s, 1);
      s += __shfl_xor(s, 2);
      s += __shfl_xor(s, 4);
      s += __shfl_xor(s, 8);
      if ((lane & 15) == 0)
        atomicAdd(&S_all[m0 + mi * 16 + (lane >> 4) * 4 + r], s);
    }

  // ---- fused diagonal: rows R0..R0+15 share b_ = R0>>5; diag cols
  // [16*b_, +16) fall in this block's panel iff 0 <= tc < 64 --------------
#pragma unroll
  for (int mi = 0; mi < 4; ++mi) {
    const int R0 = m0 + mi * 16;
    const int tc = ((R0 >> 5) << 4) - n0;
    if (tc >= 0 && tc < 64) {
      const int dn = tc >> 4;
#pragma unroll
      for (int ni = 0; ni < 4; ++ni)
        if (ni == dn) {
#pragma unroll
          for (int r = 0; r < 4; ++r) {
            float v = acc[mi][ni][r];
            v = v > 0.0f ? v : 0.0f;
            float vm = (v == 1.0f) ? 0.0f : v;
            float ps = v, ds = vm;
            ps += __shfl_xor(ps, 1); ds += __shfl_xor(ds, 1);
            ps += __shfl_xor(ps, 2); ds += __shfl_xor(ds, 2);
            ps += __shfl_xor(ps, 4); ds += __shfl_xor(ds, 4);
            ps += __shfl_xor(ps, 8); ds += __shfl_xor(ds, 8);
            if ((lane & 15) == 0) {
              const int R = R0 + (lane >> 4) * 4 + r;
              pos[R] = ps;
              diagm[R] = ds;
            }
          }
        }
    }
  }
}

// ---------------------------------------------------------------------------
// Finalize: rank + global sum. Single block, 1024 threads.
// ---------------------------------------------------------------------------
__global__ __launch_bounds__(1024) void grl_final(
    const float* __restrict__ S_all, const float* __restrict__ diagm,
    const float* __restrict__ pos, const float* __restrict__ mask,
    float* __restrict__ out) {
  __shared__ float red[16];
  const int lane = threadIdx.x & 63;
  const int wv = threadIdx.x >> 6;
  float s = 0.0f;
  for (int r = threadIdx.x; r < M_TOT; r += 1024) {
    const float neg = (S_all[r] - diagm[r]) / 255.0f;  // 255 + 1e-8 == 255.0f
    float rank = neg - pos[r] + 0.2f;
    rank = rank > 0.0f ? rank : 0.0f;
    s += rank * mask[r];
  }
#pragma unroll
  for (int off = 1; off < 64; off <<= 1) s += __shfl_xor(s, off);
  if (lane == 0) red[wv] = s;
  __syncthreads();
  if (threadIdx.x == 0) {
    float t = 0.0f;
#pragma unroll
    for (int i = 0; i < 16; ++i) t += red[i];
    out[0] = t / 256.0f;  // BETA * sum / B
  }
}

// ---------------------------------------------------------------------------
extern "C" void kernel_launch(void* const* d_in, const int* in_sizes, int n_in,
                              void* d_out, int out_size, void* d_ws, size_t ws_size,
                              hipStream_t stream) {
  const float* face = (const float*)d_in[0];
  const float* ner = (const float*)d_in[1];

  unsigned short* face_bf = (unsigned short*)d_ws;
  unsigned short* ner_bf = face_bf + (size_t)M_TOT * DIM_D;
  float* S_all = (float*)(ner_bf + (size_t)N_TOT * DIM_D);
  float* diagm = S_all + M_TOT;
  float* pos = diagm + M_TOT;
  float* mask = pos + M_TOT;

  cvt_all<<<(M_TOT + N_TOT) / 4, 256, 0, stream>>>(face, ner, face_bf, ner_bf,
                                                   mask, S_all);
  grl_wave<<<dim3(M_TOT / 64, N_TOT / 64), 64, 0, stream>>>(
      face_bf, ner_bf, S_all, pos, diagm);
  grl_final<<<1, 1024, 0, stream>>>(S_all, diagm, pos, mask, (float*)d_out);
}

// Round 15
// 63.192 us; speedup vs baseline: 1.6101x; 1.3737x over previous
//
#include <hip/hip_runtime.h>

// B=256, F=32, N=16, D=512
//   sims[b,f,c,n] = relu(face[b,f]·ner[c,n])      (8192 x 4096 NT GEMM, K=512)
//   S_all[b,f]    = sum_{c,n} masked(sims)        (masked: ==1.0 -> 0)
//   pos[b,f]      = sum_n sims[b,f,b,n]           (unmasked diagonal)
//   diag_m[b,f]   = sum_n masked(sims[b,f,b,n])
//   loss = sum(relu((S_all-diag_m)/255 - pos + 0.2) * face_mask) / 256
//
// Round 15: CONSOLIDATION. r2's best-measured GEMM core (61 us, MfmaUtil 23%,
// 0 conflicts) byte-identical, plus proven overhead cuts: diag extracted in
// the GEMM epilogue (r13-verified at this wave geometry), merged cvt+mask
// with S_all memset folded (r14-verified), 1024-thread final. 3 dispatches.

#define DIM_D 512
#define M_TOT 8192
#define N_TOT 4096

typedef __attribute__((ext_vector_type(8))) short short8v;
typedef __attribute__((ext_vector_type(4))) float f32x4;

__device__ __forceinline__ unsigned short f2bf(float f) {
  unsigned int u = __builtin_bit_cast(unsigned int, f);
  u += 0x7fffu + ((u >> 16) & 1u);
  return (unsigned short)(u >> 16);
}

// ---------------------------------------------------------------------------
// Merged cvt: face+ner fp32 -> bf16, face_mask, and S_all zeroing.
// ---------------------------------------------------------------------------
__global__ __launch_bounds__(256) void cvt_all(
    const float* __restrict__ face, const float* __restrict__ ner,
    unsigned short* __restrict__ face_bf, unsigned short* __restrict__ ner_bf,
    float* __restrict__ mask, float* __restrict__ S_all) {
  if (blockIdx.x < 8) {  // 8 blocks x 256 thr x 4 floats = 8192 = S_all
    const int i = blockIdx.x * 1024 + threadIdx.x * 4;
    *(float4*)(S_all + i) = (float4){0.f, 0.f, 0.f, 0.f};
  }
  const int gw = blockIdx.x * 4 + (threadIdx.x >> 6);
  const int lane = threadIdx.x & 63;
  const bool isFace = gw < M_TOT;
  const int row = isFace ? gw : gw - M_TOT;
  const float* src = (isFace ? face : ner) + (size_t)row * DIM_D;
  unsigned short* dst = (isFace ? face_bf : ner_bf) + (size_t)row * DIM_D;

  const float4 f0 = ((const float4*)src)[lane * 2];
  const float4 f1 = ((const float4*)src)[lane * 2 + 1];
  short8v o;
  o[0] = (short)f2bf(f0.x); o[1] = (short)f2bf(f0.y);
  o[2] = (short)f2bf(f0.z); o[3] = (short)f2bf(f0.w);
  o[4] = (short)f2bf(f1.x); o[5] = (short)f2bf(f1.y);
  o[6] = (short)f2bf(f1.z); o[7] = (short)f2bf(f1.w);
  *(short8v*)(dst + lane * 8) = o;

  if (isFace) {
    float fs = f0.x + f0.y + f0.z + f0.w + f1.x + f1.y + f1.z + f1.w;
#pragma unroll
    for (int off = 1; off < 64; off <<= 1) fs += __shfl_xor(fs, off);
    if (lane == 0) mask[row] = (fs != 0.0f) ? 1.0f : 0.0f;
  }
}

// ---------------------------------------------------------------------------
// r2's GEMM core, byte-identical: 128x128 tile, BK=32, 4 waves (2x2),
// wave-tile 64x64 = 4x4 frags of 16x16. LDS 16 KB single-buffer.
// LDS: A/B tiles [128 rows][4 k-slots of 8 bf16], slot s of row r holds
// global k-block (s ^ ((r>>1)&3)); staged with global_load_lds w=16
// (dst linear, source pre-swizzled). Fused rowsum + diag epilogue.
// ---------------------------------------------------------------------------
#define MFMA(A_, B_, C_) __builtin_amdgcn_mfma_f32_16x16x32_bf16(A_, B_, C_, 0, 0, 0)

__global__ __launch_bounds__(256) void grl_gemm_bf16(
    const unsigned short* __restrict__ A, const unsigned short* __restrict__ Bn,
    float* __restrict__ S_all, float* __restrict__ pos,
    float* __restrict__ diagm) {
  __shared__ __align__(16) unsigned short As[128 * 32];
  __shared__ __align__(16) unsigned short Bs[128 * 32];

  const int tid = threadIdx.x;
  const int lane = tid & 63;
  const int wid = tid >> 6;
  const int wr = wid >> 1;        // wave row (0..1)
  const int wc = wid & 1;         // wave col (0..1)
  const int bx = blockIdx.x;
  const int by = blockIdx.y;
  const int m0 = bx * 128;
  const int n0 = by * 128;

  // ---- stager per-lane setup (2 instrs per matrix per wave) ----
  const int g = (lane & 3) ^ ((lane >> 3) & 3);
  const int r0 = wid * 32 + (lane >> 2);
  const int r1 = r0 + 16;
  const unsigned short* gA0 = A + (size_t)(m0 + r0) * DIM_D + g * 8;
  const unsigned short* gA1 = A + (size_t)(m0 + r1) * DIM_D + g * 8;
  const unsigned short* gB0 = Bn + (size_t)(n0 + r0) * DIM_D + g * 8;
  const unsigned short* gB1 = Bn + (size_t)(n0 + r1) * DIM_D + g * 8;
  unsigned short* lA0 = As + (wid * 2 + 0) * 512;   // wave-uniform LDS bases
  unsigned short* lA1 = As + (wid * 2 + 1) * 512;
  unsigned short* lB0 = Bs + (wid * 2 + 0) * 512;
  unsigned short* lB1 = Bs + (wid * 2 + 1) * 512;

  // ---- reader per-lane setup ----
  const int slotR = (lane >> 4) ^ ((lane >> 1) & 3);
  const int aoff = (lane & 15) * 32 + slotR * 8;   // in shorts (row stride 32)

  f32x4 acc[4][4];
#pragma unroll
  for (int i = 0; i < 4; ++i)
#pragma unroll
    for (int j = 0; j < 4; ++j) acc[i][j] = (f32x4){0.f, 0.f, 0.f, 0.f};

  for (int k0 = 0; k0 < DIM_D; k0 += 32) {
    __builtin_amdgcn_global_load_lds(
        (const __attribute__((address_space(1))) void*)(gA0 + k0),
        (__attribute__((address_space(3))) void*)lA0, 16, 0, 0);
    __builtin_amdgcn_global_load_lds(
        (const __attribute__((address_space(1))) void*)(gA1 + k0),
        (__attribute__((address_space(3))) void*)lA1, 16, 0, 0);
    __builtin_amdgcn_global_load_lds(
        (const __attribute__((address_space(1))) void*)(gB0 + k0),
        (__attribute__((address_space(3))) void*)lB0, 16, 0, 0);
    __builtin_amdgcn_global_load_lds(
        (const __attribute__((address_space(1))) void*)(gB1 + k0),
        (__attribute__((address_space(3))) void*)lB1, 16, 0, 0);
    __syncthreads();   // compiler drains vmcnt(0) here

    short8v af[4], bfr[4];
#pragma unroll
    for (int mi = 0; mi < 4; ++mi)
      af[mi] = *(const short8v*)(As + (wr * 64 + mi * 16) * 32 + aoff);
#pragma unroll
    for (int ni = 0; ni < 4; ++ni)
      bfr[ni] = *(const short8v*)(Bs + (wc * 64 + ni * 16) * 32 + aoff);
#pragma unroll
    for (int mi = 0; mi < 4; ++mi)
#pragma unroll
      for (int ni = 0; ni < 4; ++ni)
        acc[mi][ni] = MFMA(af[mi], bfr[ni], acc[mi][ni]);
    __syncthreads();
  }

  // ---- fused epilogue: relu, ==1->0, row sums ----
  // C/D layout (m89-verified): col = lane&15 (n), row = (lane>>4)*4 + reg
  float rsum[4][4];   // [mi][reg]
#pragma unroll
  for (int mi = 0; mi < 4; ++mi)
#pragma unroll
    for (int r = 0; r < 4; ++r) rsum[mi][r] = 0.0f;
#pragma unroll
  for (int mi = 0; mi < 4; ++mi)
#pragma unroll
    for (int ni = 0; ni < 4; ++ni)
#pragma unroll
      for (int r = 0; r < 4; ++r) {
        float v = acc[mi][ni][r];
        v = v > 0.0f ? v : 0.0f;
        v = (v == 1.0f) ? 0.0f : v;
        rsum[mi][r] += v;
      }

#pragma unroll
  for (int mi = 0; mi < 4; ++mi)
#pragma unroll
    for (int r = 0; r < 4; ++r) {
      float s = rsum[mi][r];
      s += __shfl_xor(s, 1);
      s += __shfl_xor(s, 2);
      s += __shfl_xor(s, 4);
      s += __shfl_xor(s, 8);
      if ((lane & 15) == 0)
        atomicAdd(&S_all[m0 + wr * 64 + mi * 16 + (lane >> 4) * 4 + r], s);
    }

  // ---- fused diagonal (blocks with by == bx>>1 only; r13-verified) ------
  if (by == (bx >> 1)) {
#pragma unroll
    for (int mi = 0; mi < 4; ++mi) {
      const int R0 = m0 + wr * 64 + mi * 16;  // rows R0..R0+15 share b_
      const int tc = ((R0 >> 5) << 4) - n0;   // diag col offset in tile
      if ((tc >> 6) == wc) {
        const int dn = (tc >> 4) & 3;
#pragma unroll
        for (int ni = 0; ni < 4; ++ni)
          if (ni == dn) {
#pragma unroll
            for (int r = 0; r < 4; ++r) {
              float v = acc[mi][ni][r];
              v = v > 0.0f ? v : 0.0f;
              float vm = (v == 1.0f) ? 0.0f : v;
              float ps = v, ds = vm;
              ps += __shfl_xor(ps, 1); ds += __shfl_xor(ds, 1);
              ps += __shfl_xor(ps, 2); ds += __shfl_xor(ds, 2);
              ps += __shfl_xor(ps, 4); ds += __shfl_xor(ds, 4);
              ps += __shfl_xor(ps, 8); ds += __shfl_xor(ds, 8);
              if ((lane & 15) == 0) {
                const int R = R0 + (lane >> 4) * 4 + r;
                pos[R] = ps;
                diagm[R] = ds;
              }
            }
          }
      }
    }
  }
}

// ---------------------------------------------------------------------------
// Finalize: rank + global sum. Single block, 1024 threads.
// ---------------------------------------------------------------------------
__global__ __launch_bounds__(1024) void grl_final(
    const float* __restrict__ S_all, const float* __restrict__ diagm,
    const float* __restrict__ pos, const float* __restrict__ mask,
    float* __restrict__ out) {
  __shared__ float red[16];
  const int lane = threadIdx.x & 63;
  const int wv = threadIdx.x >> 6;
  float s = 0.0f;
  for (int r = threadIdx.x; r < M_TOT; r += 1024) {
    const float neg = (S_all[r] - diagm[r]) / 255.0f;  // 255 + 1e-8 == 255.0f
    float rank = neg - pos[r] + 0.2f;
    rank = rank > 0.0f ? rank : 0.0f;
    s += rank * mask[r];
  }
#pragma unroll
  for (int off = 1; off < 64; off <<= 1) s += __shfl_xor(s, off);
  if (lane == 0) red[wv] = s;
  __syncthreads();
  if (threadIdx.x == 0) {
    float t = 0.0f;
#pragma unroll
    for (int i = 0; i < 16; ++i) t += red[i];
    out[0] = t / 256.0f;  // BETA * sum / B
  }
}

// ---------------------------------------------------------------------------
extern "C" void kernel_launch(void* const* d_in, const int* in_sizes, int n_in,
                              void* d_out, int out_size, void* d_ws, size_t ws_size,
                              hipStream_t stream) {
  const float* face = (const float*)d_in[0];
  const float* ner = (const float*)d_in[1];

  unsigned short* face_bf = (unsigned short*)d_ws;
  unsigned short* ner_bf = face_bf + (size_t)M_TOT * DIM_D;
  float* S_all = (float*)(ner_bf + (size_t)N_TOT * DIM_D);
  float* diagm = S_all + M_TOT;
  float* pos = diagm + M_TOT;
  float* mask = pos + M_TOT;

  cvt_all<<<(M_TOT + N_TOT) / 4, 256, 0, stream>>>(face, ner, face_bf, ner_bf,
                                                   mask, S_all);
  grl_gemm_bf16<<<dim3(M_TOT / 128, N_TOT / 128), 256, 0, stream>>>(
      face_bf, ner_bf, S_all, pos, diagm);
  grl_final<<<1, 1024, 0, stream>>>(S_all, diagm, pos, mask, (float*)d_out);
}